// Round 4
// baseline (436.993 us; speedup 1.0000x reference)
//
#include <hip/hip_runtime.h>

// LIF forward scan: x [B=32, T=16, C=128, H=32, W=32] fp32 -> spikes.
// Memory-bound: 512 MiB total traffic, ~85 us floor at 6.3 TB/s.
//
// R4 structure: anti-stream-scatter. Consecutive blocks (seg fastest) cover a
// CONTIGUOUS 512-KiB slab per (b,t) as they advance in near-lockstep, so DRAM
// sees ~64 contiguous streams instead of ~20k scattered 4-KiB chunks.
// t-loop is NOT unrolled (prevents the compiler hoisting 16 strided loads);
// one-slab-ahead register prefetch keeps 2 read streams/block in flight.

#define LIF_THRESH 0.5f
#define LIF_TAU    0.25f

typedef float f4 __attribute__((ext_vector_type(4)));

constexpr int T          = 16;
constexpr int CHW        = 128 * 32 * 32;      // 131072 floats per (b,t) slab
constexpr int VEC_PER_T  = CHW / 4;            // 32768 float4 per slab
constexpr int B          = 32;
constexpr int BLK        = 256;                // threads per block
constexpr int VPT        = 4;                  // float4 per thread per slab
constexpr int SEG        = BLK * VPT;          // 1024 float4 = 16 KiB per block-slab
constexpr int SEGS_PER_B = VEC_PER_T / SEG;    // 32
constexpr int NBLOCKS    = B * SEGS_PER_B;     // 1024

__global__ __launch_bounds__(256) void lif_fwd_kernel(
    const f4* __restrict__ x, f4* __restrict__ out)
{
    const int bid = blockIdx.x;
    const int b   = bid >> 5;          // / SEGS_PER_B
    const int seg = bid & (SEGS_PER_B - 1);

    const size_t base = (size_t)b * (T * VEC_PER_T) + seg * SEG + threadIdx.x;
    const f4* xp = x   + base;
    f4*       op = out + base;

    f4 cur[VPT], nxt[VPT], mem[VPT];

#pragma unroll
    for (int j = 0; j < VPT; ++j) {
        mem[j] = (f4)(0.f);
        cur[j] = __builtin_nontemporal_load(&xp[j * BLK]);   // slab 0
    }

#pragma unroll 1
    for (int t = 0; t < T; ++t) {
        // Prefetch slab t+1 while computing slab t.
        if (t + 1 < T) {
            const f4* xq = xp + (t + 1) * VEC_PER_T;
#pragma unroll
            for (int j = 0; j < VPT; ++j)
                nxt[j] = __builtin_nontemporal_load(&xq[j * BLK]);
        }

        f4* oq = op + t * VEC_PER_T;
#pragma unroll
        for (int j = 0; j < VPT; ++j) {
            f4 m = mem[j] * LIF_TAU + cur[j];
            f4 s;
            bool fx = (m.x >= LIF_THRESH); s.x = fx ? 1.f : 0.f; m.x = fx ? 0.f : m.x;
            bool fy = (m.y >= LIF_THRESH); s.y = fy ? 1.f : 0.f; m.y = fy ? 0.f : m.y;
            bool fz = (m.z >= LIF_THRESH); s.z = fz ? 1.f : 0.f; m.z = fz ? 0.f : m.z;
            bool fw = (m.w >= LIF_THRESH); s.w = fw ? 1.f : 0.f; m.w = fw ? 0.f : m.w;
            mem[j] = m;
            __builtin_nontemporal_store(s, &oq[j * BLK]);
        }

        if (t + 1 < T) {
#pragma unroll
            for (int j = 0; j < VPT; ++j) cur[j] = nxt[j];
        }
    }
}

extern "C" void kernel_launch(void* const* d_in, const int* in_sizes, int n_in,
                              void* d_out, int out_size, void* d_ws, size_t ws_size,
                              hipStream_t stream) {
    const f4* x = (const f4*)d_in[0];
    f4* out = (f4*)d_out;

    lif_fwd_kernel<<<NBLOCKS, BLK, 0, stream>>>(x, out);
}

// Round 5
// 419.163 us; speedup vs baseline: 1.0425x; 1.0425x over previous
//
#include <hip/hip_runtime.h>

// LIF forward scan: x [B=32, T=16, C=128, H=32, W=32] fp32 -> spikes.
// Memory-bound: 512 MiB total traffic, ~85 us kernel floor at 6.3 TB/s.
// Bench dur_us includes ~250-330 us of harness restore/poison (profiled fills
// at 6.4 TB/s dominate the top-5 dispatches; our kernel is < 163 us).
//
// R5: R3 full-16-slab register batch (max MLP) + 2 float4 per thread per slab
// at offsets {i, i+256} -> each block covers 8 KiB contiguous per slab with
// perfectly unit-stride instructions, halving the machine-wide stream count.

#define LIF_THRESH 0.5f
#define LIF_TAU    0.25f

typedef float f4 __attribute__((ext_vector_type(4)));

constexpr int T         = 16;
constexpr int CHW       = 128 * 32 * 32;     // 131072 floats per (b,t) slab
constexpr int VEC_PER_T = CHW / 4;           // 32768 float4 per slab
constexpr int B         = 32;
constexpr int BLK       = 256;
constexpr int VPT       = 2;                 // float4 per thread per slab
constexpr int SEG       = BLK * VPT;         // 512 float4 = 8 KiB per block-slab
constexpr int SEGS_PER_B = VEC_PER_T / SEG;  // 64
constexpr int NBLOCKS   = B * SEGS_PER_B;    // 2048

__global__ __launch_bounds__(256) void lif_fwd_kernel(
    const f4* __restrict__ x, f4* __restrict__ out)
{
    const int bid = blockIdx.x;
    const int b   = bid >> 6;                // / SEGS_PER_B
    const int seg = bid & (SEGS_PER_B - 1);

    const size_t base = (size_t)b * (T * VEC_PER_T) + seg * SEG + threadIdx.x;
    const f4* xp = x   + base;
    f4*       op = out + base;

    // Phase 1: all 16 slabs x 2 vectors loaded back-to-back (512 B/lane in flight).
    f4 xt[T][VPT];
#pragma unroll
    for (int t = 0; t < T; ++t)
#pragma unroll
        for (int j = 0; j < VPT; ++j)
            xt[t][j] = __builtin_nontemporal_load(&xp[t * VEC_PER_T + j * BLK]);

    // Phase 2: serial recurrence in registers; store each step.
    f4 mem[VPT];
#pragma unroll
    for (int j = 0; j < VPT; ++j) mem[j] = (f4)(0.f);

#pragma unroll
    for (int t = 0; t < T; ++t) {
#pragma unroll
        for (int j = 0; j < VPT; ++j) {
            f4 m = mem[j] * LIF_TAU + xt[t][j];
            f4 s;
            bool fx = (m.x >= LIF_THRESH); s.x = fx ? 1.f : 0.f; m.x = fx ? 0.f : m.x;
            bool fy = (m.y >= LIF_THRESH); s.y = fy ? 1.f : 0.f; m.y = fy ? 0.f : m.y;
            bool fz = (m.z >= LIF_THRESH); s.z = fz ? 1.f : 0.f; m.z = fz ? 0.f : m.z;
            bool fw = (m.w >= LIF_THRESH); s.w = fw ? 1.f : 0.f; m.w = fw ? 0.f : m.w;
            mem[j] = m;
            __builtin_nontemporal_store(s, &op[t * VEC_PER_T + j * BLK]);
        }
    }
}

extern "C" void kernel_launch(void* const* d_in, const int* in_sizes, int n_in,
                              void* d_out, int out_size, void* d_ws, size_t ws_size,
                              hipStream_t stream) {
    const f4* x = (const f4*)d_in[0];
    f4* out = (f4*)d_out;

    lif_fwd_kernel<<<NBLOCKS, BLK, 0, stream>>>(x, out);
}